// Round 12
// baseline (190.473 us; speedup 1.0000x reference)
//
#include <hip/hip_runtime.h>

#define DD 1024
#define NN 16
#define SS 4096
#define BBATCH 8
#define TOK (BBATCH*SS)

typedef __attribute__((ext_vector_type(8))) __bf16 bf16x8;
typedef __attribute__((ext_vector_type(4))) __bf16 bf16x4;
typedef __attribute__((ext_vector_type(4))) float f32x4;
typedef __attribute__((ext_vector_type(16))) float f32x16;
typedef unsigned int u32;
typedef unsigned long long u64;

__device__ __forceinline__ void async16(void* lds, const void* g) {
  __builtin_amdgcn_global_load_lds(
      (const __attribute__((address_space(1))) u32*)(u64)(g),
      (__attribute__((address_space(3))) u32*)(u32)(u64)(lds), 16, 0, 0);
}

__device__ __forceinline__ float sigmoidf_(float v) {
  return 1.f / (1.f + __expf(-v));
}

// ---------------- projection v3: BM=128, 512 thr, pipelined loads, fused W-convert ----------------
__global__ __launch_bounds__(512)
void k_proj(const float* __restrict__ x, const float* __restrict__ wlf,
            const float* __restrict__ wbf, const float* __restrict__ b_lambda,
            __bf16* __restrict__ xb, float* __restrict__ lam, float* __restrict__ bx) {
  __shared__ __align__(16) __bf16 sA[128 * 32];
  __shared__ __align__(16) __bf16 sB[32 * 32];
  int tid = threadIdx.x;
  int lane = tid & 63, w = tid >> 6;
  int tok0 = blockIdx.x * 128;
  int r15 = lane & 15, kg = lane >> 4;
  int crow = tid >> 2, cg = tid & 3;
  const float* xsrc = x + (u64)(tok0 + crow) * DD + cg * 8;
  __bf16* xdst = xb + (u64)(tok0 + crow) * DD + cg * 8;
  u32 aoff = (u32)crow * 64 + ((u32)(cg ^ (crow & 3) ^ ((crow >> 2) & 3)) << 4);
  const float* wsrc = nullptr;
  u32 boff = 0;
  if (tid < 128) {
    int wrow = tid >> 2, wcg = tid & 3;
    wsrc = (wrow < 16 ? wlf + (u64)wrow * DD : wbf + (u64)(wrow - 16) * DD) + wcg * 8;
    boff = (u32)wrow * 64 + ((u32)(wcg ^ (wrow & 3)) << 4);
  }
  int arow = w * 16 + r15;
  u32 aro = (u32)arow * 64 + ((u32)(kg ^ (arow & 3) ^ ((arow >> 2) & 3)) << 4);
  u32 bro0 = (u32)r15 * 64 + ((u32)(kg ^ (r15 & 3)) << 4);
  int brow1 = 16 + r15;
  u32 bro1 = (u32)brow1 * 64 + ((u32)(kg ^ (brow1 & 3)) << 4);
  f32x4 acc0 = {}, acc1 = {};
  float4 cx0 = *(const float4*)(xsrc);
  float4 cx1 = *(const float4*)(xsrc + 4);
  float4 cw0 = {}, cw1 = {};
  if (tid < 128) { cw0 = *(const float4*)(wsrc); cw1 = *(const float4*)(wsrc + 4); }
  for (int kt = 0; kt < 32; ++kt) {
    float4 nx0, nx1, nw0 = {}, nw1 = {};
    if (kt < 31) {
      nx0 = *(const float4*)(xsrc + (kt + 1) * 32);
      nx1 = *(const float4*)(xsrc + (kt + 1) * 32 + 4);
      if (tid < 128) {
        nw0 = *(const float4*)(wsrc + (kt + 1) * 32);
        nw1 = *(const float4*)(wsrc + (kt + 1) * 32 + 4);
      }
    }
    bf16x8 cv;
    cv[0] = (__bf16)cx0.x; cv[1] = (__bf16)cx0.y; cv[2] = (__bf16)cx0.z; cv[3] = (__bf16)cx0.w;
    cv[4] = (__bf16)cx1.x; cv[5] = (__bf16)cx1.y; cv[6] = (__bf16)cx1.z; cv[7] = (__bf16)cx1.w;
    *(bf16x8*)(xdst + kt * 32) = cv;
    *(bf16x8*)((char*)sA + aoff) = cv;
    if (tid < 128) {
      bf16x8 wv;
      wv[0] = (__bf16)cw0.x; wv[1] = (__bf16)cw0.y; wv[2] = (__bf16)cw0.z; wv[3] = (__bf16)cw0.w;
      wv[4] = (__bf16)cw1.x; wv[5] = (__bf16)cw1.y; wv[6] = (__bf16)cw1.z; wv[7] = (__bf16)cw1.w;
      *(bf16x8*)((char*)sB + boff) = wv;
    }
    __syncthreads();
    bf16x8 af = *(const bf16x8*)((const char*)sA + aro);
    bf16x8 b0 = *(const bf16x8*)((const char*)sB + bro0);
    bf16x8 b1 = *(const bf16x8*)((const char*)sB + bro1);
    acc0 = __builtin_amdgcn_mfma_f32_16x16x32_bf16(af, b0, acc0, 0, 0, 0);
    acc1 = __builtin_amdgcn_mfma_f32_16x16x32_bf16(af, b1, acc1, 0, 0, 0);
    __syncthreads();
    if (kt < 31) { cx0 = nx0; cx1 = nx1; cw0 = nw0; cw1 = nw1; }
  }
  float bl = b_lambda[r15];
#pragma unroll
  for (int r = 0; r < 4; ++r) {
    int token = tok0 + w * 16 + kg * 4 + r;
    lam[token * NN + r15] = sigmoidf_(acc0[r] + bl);
    bx[token * NN + r15] = acc1[r];
  }
}

// ---------------- chunked parallel scan + W_gate convert (merged launch) ----------------
__global__ __launch_bounds__(256)
void k_scan(const float* __restrict__ lam, const float* __restrict__ bx,
            float* __restrict__ hs, const float* __restrict__ wgf,
            __bf16* __restrict__ wg) {
  if (blockIdx.x >= BBATCH * NN) {
    int i = (blockIdx.x - BBATCH * NN) * 256 + threadIdx.x;
    const float* src = wgf + (u64)i * 8;
    float4 a = *(const float4*)src, b = *(const float4*)(src + 4);
    bf16x8 o;
    o[0] = (__bf16)a.x; o[1] = (__bf16)a.y; o[2] = (__bf16)a.z; o[3] = (__bf16)a.w;
    o[4] = (__bf16)b.x; o[5] = (__bf16)b.y; o[6] = (__bf16)b.z; o[7] = (__bf16)b.w;
    *(bf16x8*)(wg + (u64)i * 8) = o;
    return;
  }
  int b = blockIdx.x >> 4, n = blockIdx.x & 15;
  int t = threadIdx.x;
  const int CH = SS / 256;  // 16
  float lv[CH], bv[CH];
  int base = (b * SS + t * CH) * NN + n;
  float a = 1.f, bacc = 0.f;
#pragma unroll
  for (int i = 0; i < CH; ++i) {
    lv[i] = lam[base + i * NN];
    bv[i] = bx[base + i * NN];
    bacc = lv[i] * bacc + bv[i];
    a *= lv[i];
  }
  __shared__ float As[2][256], Bs[2][256];
  As[0][t] = a; Bs[0][t] = bacc;
  __syncthreads();
  int cur = 0;
  for (int off = 1; off < 256; off <<= 1) {
    float a2 = As[cur][t], b2 = Bs[cur][t];
    if (t >= off) {
      float ap = As[cur][t - off], bp = Bs[cur][t - off];
      b2 = b2 + a2 * bp;
      a2 = a2 * ap;
    }
    As[cur ^ 1][t] = a2; Bs[cur ^ 1][t] = b2;
    cur ^= 1;
    __syncthreads();
  }
  float h = (t == 0) ? 0.f : Bs[cur][t - 1];
#pragma unroll
  for (int i = 0; i < CH; ++i) {
    h = lv[i] * h + bv[i];
    hs[base + i * NN] = h;
  }
}

// ---------------- gate GEMM 256x256xK=1024 — r8 4-phase skeleton, 32x32x16 MFMA ----------------
// Wave tile 128x64 = 4mf x 2nf of 32x32; acc f32x16[4][2]. Same LDS/swizzle/STAGE/vmcnt as r8.
#define STAGE(tile, M, h) do {                                                    \
    u32 lds0 = (u32)(((((tile) & 1) * 4 + (M) * 2 + (h)) << 14) + tid * 16);      \
    u64 g0 = ((M) ? bBase : aBase) + ((u64)(h) << 18) + (u64)(tile) * 128;        \
    async16(smc + lds0, (const void*)g0);                                         \
    async16(smc + lds0 + 8192, (const void*)(g0 + 131072));                       \
  } while (0)

#define MFMA_MF(mf) do {                                                          \
  _Pragma("unroll")                                                               \
  for (int s = 0; s < 4; ++s) {                                                   \
    acc[mf][0] = __builtin_amdgcn_mfma_f32_32x32x16_bf16(af[mf][s], bfr[0][s], acc[mf][0], 0, 0, 0); \
    acc[mf][1] = __builtin_amdgcn_mfma_f32_32x32x16_bf16(af[mf][s], bfr[1][s], acc[mf][1], 0, 0, 0); \
  } } while (0)

template<int YB16>
__global__ __launch_bounds__(512, 2)
void k_gemm(const __bf16* __restrict__ xb, const __bf16* __restrict__ wg,
            const float* __restrict__ hs, const float* __restrict__ wc,
            float* __restrict__ outf, __bf16* __restrict__ outb) {
  __shared__ __align__(16) char smc[131072];
  const int tid = threadIdx.x, lane = tid & 63, w = tid >> 6;
  const int l31 = lane & 31, kgrp = lane >> 5;
  const int wr = w >> 2, wcq = w & 3;       // 2 M-waves x 4 N-waves
  int bid = blockIdx.x;
  int swz = (bid & 7) * 64 + (bid >> 3);    // bijective XCD swizzle (512 % 8 == 0)
  int m = swz >> 2, n = swz & 3;
  const int tok0 = m * 256, n0 = n * 256;
  const int sslot = (tid & 7) ^ ((tid >> 3) & 7);
  const u64 aBase = (u64)(const char*)xb + (u64)(tok0 + (tid >> 3)) * 2048 + (u32)sslot * 16;
  const u64 bBase = (u64)(const char*)wg + (u64)(n0 + (tid >> 3)) * 2048 + (u32)sslot * 16;
  // frag slot offsets: slot = s*2 + kgrp, XOR row&7 == lane&7 for all frag rows
  u32 sx[4];
#pragma unroll
  for (int s = 0; s < 4; ++s)
    sx[s] = ((u32)(((s << 1) | kgrp) ^ (lane & 7))) << 4;
  const u32 lrB0 = (u32)((wcq & 1) * 64);

  f32x16 acc[4][2] = {};

  // prologue: tile0 (4 halves) + B1h0,B1h1,A1h0 -> vmcnt(6) => tile0 landed
  STAGE(0, 0, 0); STAGE(0, 0, 1); STAGE(0, 1, 0); STAGE(0, 1, 1);
  STAGE(1, 1, 0); STAGE(1, 1, 1); STAGE(1, 0, 0);
  asm volatile("s_waitcnt vmcnt(6)" ::: "memory");
  __builtin_amdgcn_s_barrier();
  asm volatile("" ::: "memory");

  for (int k = 0; k < 16; ++k) {
    const int b = k & 1;
    const char* Ah = smc + (u32)((b * 4 + wr) << 14);
    const char* Bh = smc + (u32)((b * 4 + 2 + (wcq >> 1)) << 14);
    bf16x8 af[4][4], bfr[2][4];
    // ---- P1: read A mf0 (4) + B all (8) | stage A(k+1)h1 | MFMA mf0 ----
    {
      u32 ar = (u32)l31 * 128;
#pragma unroll
      for (int s = 0; s < 4; ++s) af[0][s] = *(const bf16x8*)(Ah + ar + sx[s]);
#pragma unroll
      for (int nf = 0; nf < 2; ++nf) {
        u32 br = (lrB0 + (u32)(nf * 32 + l31)) * 128;
#pragma unroll
        for (int s = 0; s < 4; ++s) bfr[nf][s] = *(const bf16x8*)(Bh + br + sx[s]);
      }
    }
    if (k <= 14) STAGE(k + 1, 0, 1);
    __builtin_amdgcn_s_barrier();
    asm volatile("s_waitcnt lgkmcnt(0)" ::: "memory");
    __builtin_amdgcn_sched_barrier(0);
    __builtin_amdgcn_s_setprio(1);
    MFMA_MF(0);
    __builtin_amdgcn_s_setprio(0);
    __builtin_amdgcn_s_barrier();
    asm volatile("" ::: "memory");
    // ---- P2: read A mf1,mf2 (8) | stage B(k+2)h0 | MFMA mf1 ----
#pragma unroll
    for (int mf = 1; mf < 3; ++mf) {
      u32 ar = (u32)(mf * 32 + l31) * 128;
#pragma unroll
      for (int s = 0; s < 4; ++s) af[mf][s] = *(const bf16x8*)(Ah + ar + sx[s]);
    }
    if (k <= 13) STAGE(k + 2, 1, 0);
    __builtin_amdgcn_s_barrier();
    asm volatile("s_waitcnt lgkmcnt(0)" ::: "memory");
    __builtin_amdgcn_sched_barrier(0);
    __builtin_amdgcn_s_setprio(1);
    MFMA_MF(1);
    __builtin_amdgcn_s_setprio(0);
    __builtin_amdgcn_s_barrier();
    asm volatile("" ::: "memory");
    // ---- P3: read A mf3 (4) | stage B(k+2)h1 | MFMA mf2 ----
    {
      u32 ar = (u32)(3 * 32 + l31) * 128;
#pragma unroll
      for (int s = 0; s < 4; ++s) af[3][s] = *(const bf16x8*)(Ah + ar + sx[s]);
    }
    if (k <= 13) STAGE(k + 2, 1, 1);
    __builtin_amdgcn_s_barrier();
    asm volatile("s_waitcnt lgkmcnt(0)" ::: "memory");
    __builtin_amdgcn_sched_barrier(0);
    __builtin_amdgcn_s_setprio(1);
    MFMA_MF(2);
    __builtin_amdgcn_s_setprio(0);
    __builtin_amdgcn_s_barrier();
    asm volatile("" ::: "memory");
    // ---- P4: stage A(k+2)h0 | vmcnt | barrier | MFMA mf3 ----
    if (k <= 13) STAGE(k + 2, 0, 0);
    if (k <= 13)      asm volatile("s_waitcnt vmcnt(6)" ::: "memory");
    else if (k == 14) asm volatile("s_waitcnt vmcnt(0)" ::: "memory");
    __builtin_amdgcn_s_barrier();
    asm volatile("" ::: "memory");
    __builtin_amdgcn_s_setprio(1);
    MFMA_MF(3);
    __builtin_amdgcn_s_setprio(0);
  }
  asm volatile("" ::: "memory");

  // ---- epilogue: Cy via 32x32x16 MFMA (K=16 exact). hs/wc tiles [256][16] bf16 ----
  __bf16* hsH = (__bf16*)smc;             // 8KB
  __bf16* hsL = (__bf16*)(smc + 8192);    // 8KB
  __bf16* wcB = (__bf16*)(smc + 16384);   // 8KB
  {
    int row = tid >> 1, half = tid & 1;
    const float* hp = hs + (u64)(tok0 + row) * NN + half * 8;
    const float* wp2 = wc + (u64)(n0 + row) * NN + half * 8;
    float4 h0 = *(const float4*)hp, h1 = *(const float4*)(hp + 4);
    float4 w0 = *(const float4*)wp2, w1 = *(const float4*)(wp2 + 4);
    bf16x8 hh, hl, wb;
    float hv[8] = {h0.x, h0.y, h0.z, h0.w, h1.x, h1.y, h1.z, h1.w};
    float wv[8] = {w0.x, w0.y, w0.z, w0.w, w1.x, w1.y, w1.z, w1.w};
#pragma unroll
    for (int e = 0; e < 8; ++e) {
      __bf16 hi = (__bf16)hv[e];
      hh[e] = hi;
      hl[e] = (__bf16)(hv[e] - (float)hi);
      wb[e] = (__bf16)wv[e];
    }
    u32 off = (u32)row * 32 + (u32)half * 16;  // bytes
    *(bf16x8*)((char*)hsH + off) = hh;
    *(bf16x8*)((char*)hsL + off) = hl;
    *(bf16x8*)((char*)wcB + off) = wb;
  }
  __syncthreads();
  bf16x8 bw[2];
#pragma unroll
  for (int nf = 0; nf < 2; ++nf) {
    u32 off = (u32)(lrB0 + (wcq >> 1) * 128 + nf * 32 + l31) * 32 + (u32)kgrp * 16;
    bw[nf] = *(const bf16x8*)((const char*)wcB + off);
  }
  const f32x16 z16 = {};
#pragma unroll
  for (int mf = 0; mf < 4; ++mf) {
    u32 ao = (u32)(wr * 128 + mf * 32 + l31) * 32 + (u32)kgrp * 16;
    bf16x8 ah = *(const bf16x8*)((const char*)hsH + ao);
    bf16x8 al = *(const bf16x8*)((const char*)hsL + ao);
#pragma unroll
    for (int nf = 0; nf < 2; ++nf) {
      f32x16 cy = __builtin_amdgcn_mfma_f32_32x32x16_bf16(al, bw[nf], z16, 0, 0, 0);
      cy = __builtin_amdgcn_mfma_f32_32x32x16_bf16(ah, bw[nf], cy, 0, 0, 0);
      int j = wcq * 64 + nf * 32 + l31;
#pragma unroll
      for (int r = 0; r < 16; ++r) {
        int i = wr * 128 + mf * 32 + (r & 3) + 8 * (r >> 2) + 4 * kgrp;
        float g = sigmoidf_(acc[mf][nf][r]);
        u64 off = (u64)(tok0 + i) * DD + n0 + j;
        if (YB16) outb[off] = (__bf16)(g * cy[r]);
        else      outf[off] = g * cy[r];
      }
    }
  }
}

// ---------------- RMSNorm: read y bf16 (ws), write f32 out (coalesced) ----------------
__global__ __launch_bounds__(256)
void k_norm_b(const __bf16* __restrict__ yb, float* __restrict__ out,
              const float* __restrict__ rw) {
  int row = blockIdx.x * 4 + (threadIdx.x >> 6);
  int lane = threadIdx.x & 63;
  const __bf16* yrow = yb + (u64)row * DD;
  bf16x4 v[4];
  float f[16];
  float rs = 0.f;
#pragma unroll
  for (int q = 0; q < 4; ++q) {
    v[q] = *(const bf16x4*)(yrow + q * 256 + lane * 4);
#pragma unroll
    for (int e = 0; e < 4; ++e) {
      f[q * 4 + e] = (float)v[q][e];
      rs += f[q * 4 + e] * f[q * 4 + e];
    }
  }
#pragma unroll
  for (int msk = 1; msk < 64; msk <<= 1) rs += __shfl_xor(rs, msk, 64);
  float rstd = rsqrtf(rs * (1.f / DD) + 1e-6f);
  float* orow = out + (u64)row * DD;
#pragma unroll
  for (int q = 0; q < 4; ++q) {
    float4 wv = *(const float4*)(rw + q * 256 + lane * 4);
    float4 o;
    o.x = f[q * 4 + 0] * rstd * wv.x;
    o.y = f[q * 4 + 1] * rstd * wv.y;
    o.z = f[q * 4 + 2] * rstd * wv.z;
    o.w = f[q * 4 + 3] * rstd * wv.w;
    *(float4*)(orow + q * 256 + lane * 4) = o;
  }
}

// ---------------- RMSNorm fallback: in-place f32 ----------------
__global__ __launch_bounds__(256)
void k_norm_f(float* __restrict__ out, const float* __restrict__ rw) {
  int row = blockIdx.x * 4 + (threadIdx.x >> 6);
  int lane = threadIdx.x & 63;
  float4* p = (float4*)(out + (u64)row * DD);
  float4 v[4];
  float rs = 0.f;
#pragma unroll
  for (int e = 0; e < 4; ++e) {
    v[e] = p[e * 64 + lane];
    rs += v[e].x * v[e].x + v[e].y * v[e].y + v[e].z * v[e].z + v[e].w * v[e].w;
  }
#pragma unroll
  for (int msk = 1; msk < 64; msk <<= 1) rs += __shfl_xor(rs, msk, 64);
  float rstd = rsqrtf(rs * (1.f / DD) + 1e-6f);
  const float4* rwp = (const float4*)rw;
#pragma unroll
  for (int e = 0; e < 4; ++e) {
    float4 wv = rwp[e * 64 + lane];
    float4 o;
    o.x = v[e].x * rstd * wv.x;
    o.y = v[e].y * rstd * wv.y;
    o.z = v[e].z * rstd * wv.z;
    o.w = v[e].w * rstd * wv.w;
    p[e * 64 + lane] = o;
  }
}

extern "C" void kernel_launch(void* const* d_in, const int* in_sizes, int n_in,
                              void* d_out, int out_size, void* d_ws, size_t ws_size,
                              hipStream_t stream) {
  (void)in_sizes; (void)n_in; (void)out_size;
  const float* x        = (const float*)d_in[0];
  const float* W_lambda = (const float*)d_in[1];
  const float* b_lambda = (const float*)d_in[2];
  const float* W_B      = (const float*)d_in[3];
  const float* W_C      = (const float*)d_in[4];
  const float* W_gate   = (const float*)d_in[5];
  const float* rms_w    = (const float*)d_in[6];
  char* ws = (char*)d_ws;
  __bf16* xb  = (__bf16*)(ws + 0);           // 67108864 B
  __bf16* wg  = (__bf16*)(ws + 67108864);    // 2097152 B
  float*  lam = (float*)(ws + 69271552);     // 2097152 B
  float*  bx  = (float*)(ws + 71368704);     // 2097152 B
  float*  hs  = (float*)(ws + 73465856);     // 2097152 B
  __bf16* yb  = (__bf16*)(ws + 75563008);    // 67108864 B (optional)
  float*  out = (float*)d_out;
  bool yb16 = ws_size >= (size_t)(75563008ull + 67108864ull);

  k_proj<<<TOK / 128, 512, 0, stream>>>(x, W_lambda, W_B, b_lambda, xb, lam, bx);
  k_scan<<<BBATCH * NN + DD * DD / 8 / 256, 256, 0, stream>>>(lam, bx, hs, W_gate, wg);
  if (yb16) {
    k_gemm<1><<<(TOK / 256) * (DD / 256), 512, 0, stream>>>(xb, wg, hs, W_C, nullptr, yb);
    k_norm_b<<<TOK / 4, 256, 0, stream>>>(yb, out, rms_w);
  } else {
    k_gemm<0><<<(TOK / 256) * (DD / 256), 512, 0, stream>>>(xb, wg, hs, W_C, out, nullptr);
    k_norm_f<<<TOK / 4, 256, 0, stream>>>(out, rms_w);
  }
}

// Round 13
// 182.308 us; speedup vs baseline: 1.0448x; 1.0448x over previous
//
#include <hip/hip_runtime.h>

#define DD 1024
#define NN 16
#define SS 4096
#define BBATCH 8
#define TOK (BBATCH*SS)

typedef __attribute__((ext_vector_type(8))) __bf16 bf16x8;
typedef __attribute__((ext_vector_type(4))) __bf16 bf16x4;
typedef __attribute__((ext_vector_type(4))) float f32x4;
typedef unsigned int u32;
typedef unsigned long long u64;

__device__ __forceinline__ void async16(void* lds, const void* g) {
  __builtin_amdgcn_global_load_lds(
      (const __attribute__((address_space(1))) u32*)(u64)(g),
      (__attribute__((address_space(3))) u32*)(u32)(u64)(lds), 16, 0, 0);
}

__device__ __forceinline__ float sigmoidf_(float v) {
  return 1.f / (1.f + __expf(-v));
}

// ---------------- projection v4: BM=64, 256 thr, grid 512 (2 blocks/CU), pipelined ----------------
// [lam|Bx](32768x32) = x @ [W_lambda;W_B]^T; fuses x f32->bf16 (xb) and W f32->bf16.
__global__ __launch_bounds__(256)
void k_proj(const float* __restrict__ x, const float* __restrict__ wlf,
            const float* __restrict__ wbf, const float* __restrict__ b_lambda,
            __bf16* __restrict__ xb, float* __restrict__ lam, float* __restrict__ bx) {
  __shared__ __align__(16) __bf16 sA[64 * 32];   // 4KB, 64B rows, XOR swizzle
  __shared__ __align__(16) __bf16 sB[32 * 32];   // 2KB
  int tid = threadIdx.x;
  int lane = tid & 63, w = tid >> 6;             // 4 waves
  int tok0 = blockIdx.x * 64;
  int r15 = lane & 15, kg = lane >> 4;
  // x: thread -> (row=tid>>2 in 0..63, col-group=tid&3), 8 floats per kt
  int crow = tid >> 2, cg = tid & 3;
  const float* xsrc = x + (u64)(tok0 + crow) * DD + cg * 8;
  __bf16* xdst = xb + (u64)(tok0 + crow) * DD + cg * 8;
  u32 aoff = (u32)crow * 64 + ((u32)(cg ^ (crow & 3) ^ ((crow >> 2) & 3)) << 4);
  // W: threads 0-127 -> (wrow=tid>>2 in 0..31, wcg=tid&3); rows 0-15 W_lambda, 16-31 W_B
  const float* wsrc = nullptr;
  u32 boff = 0;
  if (tid < 128) {
    int wrow = tid >> 2, wcg = tid & 3;
    wsrc = (wrow < 16 ? wlf + (u64)wrow * DD : wbf + (u64)(wrow - 16) * DD) + wcg * 8;
    boff = (u32)wrow * 64 + ((u32)(wcg ^ (wrow & 3)) << 4);
  }
  // fragment offsets: wave w owns M-tile w (rows w*16..w*16+15)
  int arow = w * 16 + r15;
  u32 aro = (u32)arow * 64 + ((u32)(kg ^ (arow & 3) ^ ((arow >> 2) & 3)) << 4);
  u32 bro0 = (u32)r15 * 64 + ((u32)(kg ^ (r15 & 3)) << 4);
  int brow1 = 16 + r15;
  u32 bro1 = (u32)brow1 * 64 + ((u32)(kg ^ (brow1 & 3)) << 4);
  f32x4 acc0 = {}, acc1 = {};
  float4 cx0 = *(const float4*)(xsrc);
  float4 cx1 = *(const float4*)(xsrc + 4);
  float4 cw0 = {}, cw1 = {};
  if (tid < 128) { cw0 = *(const float4*)(wsrc); cw1 = *(const float4*)(wsrc + 4); }
  for (int kt = 0; kt < 32; ++kt) {
    float4 nx0, nx1, nw0 = {}, nw1 = {};
    if (kt < 31) {
      nx0 = *(const float4*)(xsrc + (kt + 1) * 32);
      nx1 = *(const float4*)(xsrc + (kt + 1) * 32 + 4);
      if (tid < 128) {
        nw0 = *(const float4*)(wsrc + (kt + 1) * 32);
        nw1 = *(const float4*)(wsrc + (kt + 1) * 32 + 4);
      }
    }
    bf16x8 cv;
    cv[0] = (__bf16)cx0.x; cv[1] = (__bf16)cx0.y; cv[2] = (__bf16)cx0.z; cv[3] = (__bf16)cx0.w;
    cv[4] = (__bf16)cx1.x; cv[5] = (__bf16)cx1.y; cv[6] = (__bf16)cx1.z; cv[7] = (__bf16)cx1.w;
    *(bf16x8*)(xdst + kt * 32) = cv;
    *(bf16x8*)((char*)sA + aoff) = cv;
    if (tid < 128) {
      bf16x8 wv;
      wv[0] = (__bf16)cw0.x; wv[1] = (__bf16)cw0.y; wv[2] = (__bf16)cw0.z; wv[3] = (__bf16)cw0.w;
      wv[4] = (__bf16)cw1.x; wv[5] = (__bf16)cw1.y; wv[6] = (__bf16)cw1.z; wv[7] = (__bf16)cw1.w;
      *(bf16x8*)((char*)sB + boff) = wv;
    }
    __syncthreads();
    bf16x8 af = *(const bf16x8*)((const char*)sA + aro);
    bf16x8 b0 = *(const bf16x8*)((const char*)sB + bro0);
    bf16x8 b1 = *(const bf16x8*)((const char*)sB + bro1);
    acc0 = __builtin_amdgcn_mfma_f32_16x16x32_bf16(af, b0, acc0, 0, 0, 0);
    acc1 = __builtin_amdgcn_mfma_f32_16x16x32_bf16(af, b1, acc1, 0, 0, 0);
    __syncthreads();
    if (kt < 31) { cx0 = nx0; cx1 = nx1; cw0 = nw0; cw1 = nw1; }
  }
  float bl = b_lambda[r15];
#pragma unroll
  for (int r = 0; r < 4; ++r) {
    int token = tok0 + w * 16 + kg * 4 + r;
    lam[token * NN + r15] = sigmoidf_(acc0[r] + bl);
    bx[token * NN + r15] = acc1[r];
  }
}

// ---------------- chunked parallel scan + W_gate convert (merged launch) ----------------
__global__ __launch_bounds__(256)
void k_scan(const float* __restrict__ lam, const float* __restrict__ bx,
            float* __restrict__ hs, const float* __restrict__ wgf,
            __bf16* __restrict__ wg) {
  if (blockIdx.x >= BBATCH * NN) {
    int i = (blockIdx.x - BBATCH * NN) * 256 + threadIdx.x;
    const float* src = wgf + (u64)i * 8;
    float4 a = *(const float4*)src, b = *(const float4*)(src + 4);
    bf16x8 o;
    o[0] = (__bf16)a.x; o[1] = (__bf16)a.y; o[2] = (__bf16)a.z; o[3] = (__bf16)a.w;
    o[4] = (__bf16)b.x; o[5] = (__bf16)b.y; o[6] = (__bf16)b.z; o[7] = (__bf16)b.w;
    *(bf16x8*)(wg + (u64)i * 8) = o;
    return;
  }
  int b = blockIdx.x >> 4, n = blockIdx.x & 15;
  int t = threadIdx.x;
  const int CH = SS / 256;  // 16
  float lv[CH], bv[CH];
  int base = (b * SS + t * CH) * NN + n;
  float a = 1.f, bacc = 0.f;
#pragma unroll
  for (int i = 0; i < CH; ++i) {
    lv[i] = lam[base + i * NN];
    bv[i] = bx[base + i * NN];
    bacc = lv[i] * bacc + bv[i];
    a *= lv[i];
  }
  __shared__ float As[2][256], Bs[2][256];
  As[0][t] = a; Bs[0][t] = bacc;
  __syncthreads();
  int cur = 0;
  for (int off = 1; off < 256; off <<= 1) {
    float a2 = As[cur][t], b2 = Bs[cur][t];
    if (t >= off) {
      float ap = As[cur][t - off], bp = Bs[cur][t - off];
      b2 = b2 + a2 * bp;
      a2 = a2 * ap;
    }
    As[cur ^ 1][t] = a2; Bs[cur ^ 1][t] = b2;
    cur ^= 1;
    __syncthreads();
  }
  float h = (t == 0) ? 0.f : Bs[cur][t - 1];
#pragma unroll
  for (int i = 0; i < CH; ++i) {
    h = lv[i] * h + bv[i];
    hs[base + i * NN] = h;
  }
}

// ---------------- gate GEMM 256x256xK=1024 — r8/r11 4-phase 16x16 schedule (verified best) ----------------
#define STAGE(tile, M, h) do {                                                    \
    u32 lds0 = (u32)(((((tile) & 1) * 4 + (M) * 2 + (h)) << 14) + tid * 16);      \
    u64 g0 = ((M) ? bBase : aBase) + ((u64)(h) << 18) + (u64)(tile) * 128;        \
    async16(smc + lds0, (const void*)g0);                                         \
    async16(smc + lds0 + 8192, (const void*)(g0 + 131072));                       \
  } while (0)

template<int YB16>
__global__ __launch_bounds__(512, 2)
void k_gemm(const __bf16* __restrict__ xb, const __bf16* __restrict__ wg,
            const float* __restrict__ hs, const float* __restrict__ wc,
            float* __restrict__ outf, __bf16* __restrict__ outb) {
  __shared__ __align__(16) char smc[131072];
  const int tid = threadIdx.x, lane = tid & 63, w = tid >> 6;
  const int r15 = lane & 15, kg = lane >> 4;
  const int wr = w >> 2, wcq = w & 3;       // 2 M-waves x 4 N-waves
  int bid = blockIdx.x;
  int swz = (bid & 7) * 64 + (bid >> 3);    // bijective XCD swizzle (512 % 8 == 0)
  int m = swz >> 2, n = swz & 3;
  const int tok0 = m * 256, n0 = n * 256;
  const int sslot = (tid & 7) ^ ((tid >> 3) & 7);
  const u64 aBase = (u64)(const char*)xb + (u64)(tok0 + (tid >> 3)) * 2048 + (u32)sslot * 16;
  const u64 bBase = (u64)(const char*)wg + (u64)(n0 + (tid >> 3)) * 2048 + (u32)sslot * 16;
  const u32 sxa0 = (u32)(((0 | kg) ^ (r15 & 7)) * 16);
  const u32 sxa1 = (u32)(((4 | kg) ^ (r15 & 7)) * 16);
  const u32 lrB0 = (u32)((wcq & 1) * 64);

  f32x4 acc[8][4] = {};

  // prologue: tile0 (4 halves) + B1h0,B1h1,A1h0 -> vmcnt(6) => tile0 landed
  STAGE(0, 0, 0); STAGE(0, 0, 1); STAGE(0, 1, 0); STAGE(0, 1, 1);
  STAGE(1, 1, 0); STAGE(1, 1, 1); STAGE(1, 0, 0);
  asm volatile("s_waitcnt vmcnt(6)" ::: "memory");
  __builtin_amdgcn_s_barrier();
  asm volatile("" ::: "memory");

  for (int k = 0; k < 16; ++k) {
    const int b = k & 1;
    const char* Ah = smc + (u32)((b * 4 + wr) << 14);
    const char* Bh = smc + (u32)((b * 4 + 2 + (wcq >> 1)) << 14);
    bf16x8 af[8][2], bfr[4][2];
    // ---- P1: read A m0-1 + B all (12 ds) | stage A(k+1)h1 | MFMA m0-1 ----
#pragma unroll
    for (int mt = 0; mt < 2; ++mt) {
      u32 ro = (u32)(mt * 16 + r15) * 128;
      af[mt][0] = *(const bf16x8*)(Ah + ro + sxa0);
      af[mt][1] = *(const bf16x8*)(Ah + ro + sxa1);
    }
#pragma unroll
    for (int nt = 0; nt < 4; ++nt) {
      u32 ro = (lrB0 + (u32)(nt * 16 + r15)) * 128;
      bfr[nt][0] = *(const bf16x8*)(Bh + ro + sxa0);
      bfr[nt][1] = *(const bf16x8*)(Bh + ro + sxa1);
    }
    if (k <= 14) STAGE(k + 1, 0, 1);
    __builtin_amdgcn_s_barrier();
    asm volatile("s_waitcnt lgkmcnt(0)" ::: "memory");
    __builtin_amdgcn_sched_barrier(0);
    __builtin_amdgcn_s_setprio(1);
#pragma unroll
    for (int mt = 0; mt < 2; ++mt)
#pragma unroll
      for (int nt = 0; nt < 4; ++nt) {
        acc[mt][nt] = __builtin_amdgcn_mfma_f32_16x16x32_bf16(af[mt][0], bfr[nt][0], acc[mt][nt], 0, 0, 0);
        acc[mt][nt] = __builtin_amdgcn_mfma_f32_16x16x32_bf16(af[mt][1], bfr[nt][1], acc[mt][nt], 0, 0, 0);
      }
    __builtin_amdgcn_s_setprio(0);
    __builtin_amdgcn_s_barrier();
    asm volatile("" ::: "memory");
    // ---- P2: read A m2-5 (8 ds) | stage B(k+2)h0 | MFMA m2-3 ----
#pragma unroll
    for (int mt = 2; mt < 6; ++mt) {
      u32 ro = (u32)(mt * 16 + r15) * 128;
      af[mt][0] = *(const bf16x8*)(Ah + ro + sxa0);
      af[mt][1] = *(const bf16x8*)(Ah + ro + sxa1);
    }
    if (k <= 13) STAGE(k + 2, 1, 0);
    __builtin_amdgcn_s_barrier();
    asm volatile("s_waitcnt lgkmcnt(0)" ::: "memory");
    __builtin_amdgcn_sched_barrier(0);
    __builtin_amdgcn_s_setprio(1);
#pragma unroll
    for (int mt = 2; mt < 4; ++mt)
#pragma unroll
      for (int nt = 0; nt < 4; ++nt) {
        acc[mt][nt] = __builtin_amdgcn_mfma_f32_16x16x32_bf16(af[mt][0], bfr[nt][0], acc[mt][nt], 0, 0, 0);
        acc[mt][nt] = __builtin_amdgcn_mfma_f32_16x16x32_bf16(af[mt][1], bfr[nt][1], acc[mt][nt], 0, 0, 0);
      }
    __builtin_amdgcn_s_setprio(0);
    __builtin_amdgcn_s_barrier();
    asm volatile("" ::: "memory");
    // ---- P3: read A m6-7 (4 ds) | stage B(k+2)h1 | MFMA m4-5 ----
#pragma unroll
    for (int mt = 6; mt < 8; ++mt) {
      u32 ro = (u32)(mt * 16 + r15) * 128;
      af[mt][0] = *(const bf16x8*)(Ah + ro + sxa0);
      af[mt][1] = *(const bf16x8*)(Ah + ro + sxa1);
    }
    if (k <= 13) STAGE(k + 2, 1, 1);
    __builtin_amdgcn_s_barrier();
    asm volatile("s_waitcnt lgkmcnt(0)" ::: "memory");
    __builtin_amdgcn_sched_barrier(0);
    __builtin_amdgcn_s_setprio(1);
#pragma unroll
    for (int mt = 4; mt < 6; ++mt)
#pragma unroll
      for (int nt = 0; nt < 4; ++nt) {
        acc[mt][nt] = __builtin_amdgcn_mfma_f32_16x16x32_bf16(af[mt][0], bfr[nt][0], acc[mt][nt], 0, 0, 0);
        acc[mt][nt] = __builtin_amdgcn_mfma_f32_16x16x32_bf16(af[mt][1], bfr[nt][1], acc[mt][nt], 0, 0, 0);
      }
    __builtin_amdgcn_s_setprio(0);
    __builtin_amdgcn_s_barrier();
    asm volatile("" ::: "memory");
    // ---- P4: stage A(k+2)h0 | vmcnt | barrier | MFMA m6-7 ----
    if (k <= 13) STAGE(k + 2, 0, 0);
    if (k <= 13)      asm volatile("s_waitcnt vmcnt(6)" ::: "memory");
    else if (k == 14) asm volatile("s_waitcnt vmcnt(0)" ::: "memory");
    __builtin_amdgcn_s_barrier();
    asm volatile("" ::: "memory");
    __builtin_amdgcn_s_setprio(1);
#pragma unroll
    for (int mt = 6; mt < 8; ++mt)
#pragma unroll
      for (int nt = 0; nt < 4; ++nt) {
        acc[mt][nt] = __builtin_amdgcn_mfma_f32_16x16x32_bf16(af[mt][0], bfr[nt][0], acc[mt][nt], 0, 0, 0);
        acc[mt][nt] = __builtin_amdgcn_mfma_f32_16x16x32_bf16(af[mt][1], bfr[nt][1], acc[mt][nt], 0, 0, 0);
      }
    __builtin_amdgcn_s_setprio(0);
  }
  asm volatile("" ::: "memory");

  // ---- epilogue: Cy via MFMA (verified). Tiles 64B rows, k16-31 zero, slot^(row&3) ----
  __bf16* hsH = (__bf16*)smc;
  __bf16* hsL = (__bf16*)(smc + 16384);
  __bf16* wcB = (__bf16*)(smc + 32768);
  {
    int row = tid >> 1, half = tid & 1;
    const float* hp = hs + (u64)(tok0 + row) * NN + half * 8;
    const float* wp2 = wc + (u64)(n0 + row) * NN + half * 8;
    float4 h0 = *(const float4*)hp, h1 = *(const float4*)(hp + 4);
    float4 w0 = *(const float4*)wp2, w1 = *(const float4*)(wp2 + 4);
    bf16x8 hh, hl, wb, zz = {};
    float hv[8] = {h0.x, h0.y, h0.z, h0.w, h1.x, h1.y, h1.z, h1.w};
    float wv[8] = {w0.x, w0.y, w0.z, w0.w, w1.x, w1.y, w1.z, w1.w};
#pragma unroll
    for (int e = 0; e < 8; ++e) {
      __bf16 hi = (__bf16)hv[e];
      hh[e] = hi;
      hl[e] = (__bf16)(hv[e] - (float)hi);
      wb[e] = (__bf16)wv[e];
    }
    u32 realOff = (u32)row * 32 + (u32)((half ^ (row & 3)) << 3);
    u32 zeroOff = (u32)row * 32 + (u32)(((2 + half) ^ (row & 3)) << 3);
    *(bf16x8*)(hsH + realOff) = hh;  *(bf16x8*)(hsH + zeroOff) = zz;
    *(bf16x8*)(hsL + realOff) = hl;  *(bf16x8*)(hsL + zeroOff) = zz;
    *(bf16x8*)(wcB + realOff) = wb;  *(bf16x8*)(wcB + zeroOff) = zz;
  }
  __syncthreads();
  bf16x8 bw[4];
#pragma unroll
  for (int nt = 0; nt < 4; ++nt) {
    int row = wcq * 64 + nt * 16 + r15;
    bw[nt] = *(const bf16x8*)(wcB + row * 32 + ((kg ^ (row & 3)) << 3));
  }
  const f32x4 zero4 = {};
#pragma unroll
  for (int mt = 0; mt < 8; ++mt) {
    int arow = wr * 128 + mt * 16 + r15;
    u32 ao = (u32)arow * 32 + (u32)((kg ^ (arow & 3)) << 3);
    bf16x8 ah = *(const bf16x8*)(hsH + ao);
    bf16x8 al = *(const bf16x8*)(hsL + ao);
#pragma unroll
    for (int nt = 0; nt < 4; ++nt) {
      f32x4 cy4 = __builtin_amdgcn_mfma_f32_16x16x32_bf16(al, bw[nt], zero4, 0, 0, 0);
      cy4 = __builtin_amdgcn_mfma_f32_16x16x32_bf16(ah, bw[nt], cy4, 0, 0, 0);
      int j = wcq * 64 + nt * 16 + r15;
#pragma unroll
      for (int r = 0; r < 4; ++r) {
        int i = wr * 128 + mt * 16 + kg * 4 + r;
        float g = sigmoidf_(acc[mt][nt][r]);
        u64 off = (u64)(tok0 + i) * DD + n0 + j;
        if (YB16) outb[off] = (__bf16)(g * cy4[r]);
        else      outf[off] = g * cy4[r];
      }
    }
  }
}

// ---------------- RMSNorm: read y bf16 (ws), write f32 out (coalesced) ----------------
__global__ __launch_bounds__(256)
void k_norm_b(const __bf16* __restrict__ yb, float* __restrict__ out,
              const float* __restrict__ rw) {
  int row = blockIdx.x * 4 + (threadIdx.x >> 6);
  int lane = threadIdx.x & 63;
  const __bf16* yrow = yb + (u64)row * DD;
  bf16x4 v[4];
  float f[16];
  float rs = 0.f;
#pragma unroll
  for (int q = 0; q < 4; ++q) {
    v[q] = *(const bf16x4*)(yrow + q * 256 + lane * 4);
#pragma unroll
    for (int e = 0; e < 4; ++e) {
      f[q * 4 + e] = (float)v[q][e];
      rs += f[q * 4 + e] * f[q * 4 + e];
    }
  }
#pragma unroll
  for (int msk = 1; msk < 64; msk <<= 1) rs += __shfl_xor(rs, msk, 64);
  float rstd = rsqrtf(rs * (1.f / DD) + 1e-6f);
  float* orow = out + (u64)row * DD;
#pragma unroll
  for (int q = 0; q < 4; ++q) {
    float4 wv = *(const float4*)(rw + q * 256 + lane * 4);
    float4 o;
    o.x = f[q * 4 + 0] * rstd * wv.x;
    o.y = f[q * 4 + 1] * rstd * wv.y;
    o.z = f[q * 4 + 2] * rstd * wv.z;
    o.w = f[q * 4 + 3] * rstd * wv.w;
    *(float4*)(orow + q * 256 + lane * 4) = o;
  }
}

// ---------------- RMSNorm fallback: in-place f32 ----------------
__global__ __launch_bounds__(256)
void k_norm_f(float* __restrict__ out, const float* __restrict__ rw) {
  int row = blockIdx.x * 4 + (threadIdx.x >> 6);
  int lane = threadIdx.x & 63;
  float4* p = (float4*)(out + (u64)row * DD);
  float4 v[4];
  float rs = 0.f;
#pragma unroll
  for (int e = 0; e < 4; ++e) {
    v[e] = p[e * 64 + lane];
    rs += v[e].x * v[e].x + v[e].y * v[e].y + v[e].z * v[e].z + v[e].w * v[e].w;
  }
#pragma unroll
  for (int msk = 1; msk < 64; msk <<= 1) rs += __shfl_xor(rs, msk, 64);
  float rstd = rsqrtf(rs * (1.f / DD) + 1e-6f);
  const float4* rwp = (const float4*)rw;
#pragma unroll
  for (int e = 0; e < 4; ++e) {
    float4 wv = rwp[e * 64 + lane];
    float4 o;
    o.x = v[e].x * rstd * wv.x;
    o.y = v[e].y * rstd * wv.y;
    o.z = v[e].z * rstd * wv.z;
    o.w = v[e].w * rstd * wv.w;
    p[e * 64 + lane] = o;
  }
}

extern "C" void kernel_launch(void* const* d_in, const int* in_sizes, int n_in,
                              void* d_out, int out_size, void* d_ws, size_t ws_size,
                              hipStream_t stream) {
  (void)in_sizes; (void)n_in; (void)out_size;
  const float* x        = (const float*)d_in[0];
  const float* W_lambda = (const float*)d_in[1];
  const float* b_lambda = (const float*)d_in[2];
  const float* W_B      = (const float*)d_in[3];
  const float* W_C      = (const float*)d_in[4];
  const float* W_gate   = (const float*)d_in[5];
  const float* rms_w    = (const float*)d_in[6];
  char* ws = (char*)d_ws;
  __bf16* xb  = (__bf16*)(ws + 0);           // 67108864 B
  __bf16* wg  = (__bf16*)(ws + 67108864);    // 2097152 B
  float*  lam = (float*)(ws + 69271552);     // 2097152 B
  float*  bx  = (float*)(ws + 71368704);     // 2097152 B
  float*  hs  = (float*)(ws + 73465856);     // 2097152 B
  __bf16* yb  = (__bf16*)(ws + 75563008);    // 67108864 B (optional)
  float*  out = (float*)d_out;
  bool yb16 = ws_size >= (size_t)(75563008ull + 67108864ull);

  k_proj<<<TOK / 64, 256, 0, stream>>>(x, W_lambda, W_B, b_lambda, xb, lam, bx);
  k_scan<<<BBATCH * NN + DD * DD / 8 / 256, 256, 0, stream>>>(lam, bx, hs, W_gate, wg);
  if (yb16) {
    k_gemm<1><<<(TOK / 256) * (DD / 256), 512, 0, stream>>>(xb, wg, hs, W_C, nullptr, yb);
    k_norm_b<<<TOK / 4, 256, 0, stream>>>(yb, out, rms_w);
  } else {
    k_gemm<0><<<(TOK / 256) * (DD / 256), 512, 0, stream>>>(xb, wg, hs, W_C, out, nullptr);
    k_norm_f<<<TOK / 4, 256, 0, stream>>>(out, rms_w);
  }
}